// Round 2
// baseline (2190.997 us; speedup 1.0000x reference)
//
#include <hip/hip_runtime.h>
#include <hip/hip_bf16.h>
#include <math.h>

// ---------------------------------------------------------------------------
// Types
// ---------------------------------------------------------------------------
typedef __bf16 bf16_t;
typedef __bf16 bf16x8 __attribute__((ext_vector_type(8)));
typedef __bf16 bf16x4 __attribute__((ext_vector_type(4)));
typedef float  f32x4  __attribute__((ext_vector_type(4)));

#define MFMA_BF16(a, b, c) __builtin_amdgcn_mfma_f32_16x16x32_bf16((a), (b), (c), 0, 0, 0)

typedef const void __attribute__((address_space(1)))* gas_ptr;
typedef void       __attribute__((address_space(3)))* las_ptr;

__device__ __forceinline__ void gload_lds16(const void* g, void* l) {
  // global -> LDS direct, 16B per lane. LDS dest is wave-uniform base + lane*16.
  __builtin_amdgcn_global_load_lds((gas_ptr)g, (las_ptr)l, 16, 0, 0);
}

// ---------------------------------------------------------------------------
// Model constants
// ---------------------------------------------------------------------------
static constexpr int B_ = 4, S_ = 1024, D_ = 1024, HF_ = 4096, V_ = 32000;
static constexpr int NH_ = 16, HD_ = 64;
static constexpr int TOK_ = B_ * S_;  // 4096

// ---------------------------------------------------------------------------
// fp32 -> bf16 conversion (vectorized x4)
// ---------------------------------------------------------------------------
__global__ __launch_bounds__(256) void cvt_f32_bf16(const float* __restrict__ in,
                                                    bf16_t* __restrict__ out, int n4) {
  int i = blockIdx.x * 256 + threadIdx.x;
  if (i < n4) {
    float4 v = ((const float4*)in)[i];
    bf16x4 o;
    o[0] = (bf16_t)v.x; o[1] = (bf16_t)v.y; o[2] = (bf16_t)v.z; o[3] = (bf16_t)v.w;
    ((bf16x4*)out)[i] = o;
  }
}

// ---------------------------------------------------------------------------
// Sinusoidal positional encoding table
// ---------------------------------------------------------------------------
__global__ __launch_bounds__(256) void pe_kernel(float* __restrict__ pe) {
  const int s = blockIdx.x;
  for (int i = threadIdx.x; i < D_ / 2; i += 256) {
    float div = expf((2.0f * (float)i) * (-9.210340371976184f / (float)D_)); // ln(10000)
    float a = (float)s * div;
    pe[(size_t)s * D_ + 2 * i]     = sinf(a);
    pe[(size_t)s * D_ + 2 * i + 1] = cosf(a);
  }
}

// ---------------------------------------------------------------------------
// Embedding: h[t][d] = emb_W[x[t]][d] * 32 + pe[t % S][d]
// ---------------------------------------------------------------------------
__global__ __launch_bounds__(256) void embed_kernel(const int* __restrict__ x,
                                                    const float* __restrict__ embW,
                                                    const float* __restrict__ pe,
                                                    float* __restrict__ h) {
  int i = blockIdx.x * 256 + threadIdx.x;
  int token = i >> 8;
  int c4 = i & 255;
  int idx = x[token];
  float4 e = ((const float4*)(embW + (size_t)idx * D_))[c4];
  float4 p = ((const float4*)(pe + (size_t)(token & (S_ - 1)) * D_))[c4];
  float4 o;
  o.x = e.x * 32.0f + p.x; o.y = e.y * 32.0f + p.y;
  o.z = e.z * 32.0f + p.z; o.w = e.w * 32.0f + p.w;
  ((float4*)(h + (size_t)token * D_))[c4] = o;
}

// ---------------------------------------------------------------------------
// a_in = h + LayerNorm(h)*g + b   -> bf16
// ---------------------------------------------------------------------------
__global__ __launch_bounds__(256) void ln_res_kernel(const float* __restrict__ h,
                                                     const float* __restrict__ gamma,
                                                     const float* __restrict__ beta,
                                                     bf16_t* __restrict__ out) {
  const int row = blockIdx.x;
  const int tid = threadIdx.x;
  const float4 v = ((const float4*)(h + (size_t)row * D_))[tid];
  float s  = v.x + v.y + v.z + v.w;
  float s2 = v.x * v.x + v.y * v.y + v.z * v.z + v.w * v.w;
#pragma unroll
  for (int m = 1; m < 64; m <<= 1) {
    s  += __shfl_xor(s, m, 64);
    s2 += __shfl_xor(s2, m, 64);
  }
  __shared__ float red[2][4];
  const int wave = tid >> 6, lane = tid & 63;
  if (lane == 0) { red[0][wave] = s; red[1][wave] = s2; }
  __syncthreads();
  s  = red[0][0] + red[0][1] + red[0][2] + red[0][3];
  s2 = red[1][0] + red[1][1] + red[1][2] + red[1][3];
  const float mu   = s * (1.0f / D_);
  const float rstd = rsqrtf(s2 * (1.0f / D_) - mu * mu + 1e-5f);
  const float4 g4 = ((const float4*)gamma)[tid];
  const float4 b4 = ((const float4*)beta)[tid];
  bf16x4 o;
  o[0] = (bf16_t)(v.x + (v.x - mu) * rstd * g4.x + b4.x);
  o[1] = (bf16_t)(v.y + (v.y - mu) * rstd * g4.y + b4.y);
  o[2] = (bf16_t)(v.z + (v.z - mu) * rstd * g4.z + b4.z);
  o[3] = (bf16_t)(v.w + (v.w - mu) * rstd * g4.w + b4.w);
  ((bf16x4*)(out + (size_t)row * D_))[tid] = o;
}

// ---------------------------------------------------------------------------
// Pipelined GEMM: C[4096,N] = A[4096,K] @ W[N,K]^T.
// Tile 256x128, 8 waves (4M x 2N), BK=32, 4 rotating LDS buffers (96 KB).
// Counted vmcnt(6) steady-state (never drains in main loop), 1 barrier/tile,
// counted lgkmcnt(2), setprio around MFMA, XOR-swizzled LDS (both sides),
// M-fastest block order + bijective XCD swizzle. GM = M/256 = 16 fixed.
// Epilogues: 0 QKV-scatter, 2 bias+relu->bf16, 4 bias->f32.
// ---------------------------------------------------------------------------
__device__ __forceinline__ int xorpat(int r) {
  return ((r & 1) << 5) | ((r & 2) << 3);  // row -> byte-XOR within 64B row
}

template <int EPI>
__global__ __launch_bounds__(512, 2) void gemm_pipe(
    const bf16_t* __restrict__ A, const bf16_t* __restrict__ W, int N, int K,
    float* __restrict__ fout, const float* __restrict__ bias, bf16_t* __restrict__ bout,
    bf16_t* __restrict__ qb, bf16_t* __restrict__ kb, bf16_t* __restrict__ vtb) {
  __shared__ bf16_t sA[4][256 * 32];  // 64 KB, row = 64 B
  __shared__ bf16_t sB[4][128 * 32];  // 32 KB

  const int tid = threadIdx.x;
  const int wave = tid >> 6, lane = tid & 63;
  const int row16 = lane & 15, kgrp = lane >> 4;
  const int wm = wave >> 1, wn = wave & 1;

  // --- block swizzle: XCD-bijective (m204), then M-fastest decode ---
  const int nb = gridDim.x;          // multiple of 8 for all our shapes
  const int qq = nb >> 3, rr = nb & 7;
  const int xcd = blockIdx.x & 7, lid = blockIdx.x >> 3;
  const int logical = (xcd < rr ? xcd * (qq + 1) : rr * (qq + 1) + (xcd - rr) * qq) + lid;
  const int m0 = (logical & 15) * 256;   // M fastest (GM=16)
  const int n0 = (logical >> 4) * 128;

  // --- staging source addresses (inverse-swizzled global, linear LDS dest) ---
  const int srow = lane >> 2;           // 0..15
  const int scol = (lane & 3) * 16;     // byte 0..48
  const int ar0 = wave * 16 + srow;           // A rows, op 0
  const int ar1 = 128 + wave * 16 + srow;     // A rows, op 1
  const int br0 = wave * 16 + srow;           // B rows
  const char* gA0 = (const char*)(A + (size_t)(m0 + ar0) * K) + (scol ^ xorpat(ar0));
  const char* gA1 = (const char*)(A + (size_t)(m0 + ar1) * K) + (scol ^ xorpat(ar1));
  const char* gB0 = (const char*)(W + (size_t)(n0 + br0) * K) + (scol ^ xorpat(br0));
  // LDS dests (wave-uniform base; HW adds lane*16)
  char* const dA0 = (char*)sA[0] + wave * 1024;
  char* const dA1 = (char*)sA[0] + (8 + wave) * 1024;
  char* const dB0 = (char*)sB[0] + wave * 1024;
  const size_t bufA = 256 * 32 * 2, bufB = 128 * 32 * 2;

  // --- swizzled ds_read byte offsets ---
  int aoff[4], boff[4];
#pragma unroll
  for (int m = 0; m < 4; m++) {
    const int r = wm * 64 + m * 16 + row16;
    aoff[m] = r * 64 + ((kgrp * 16) ^ xorpat(r));
  }
#pragma unroll
  for (int n = 0; n < 4; n++) {
    const int r = wn * 64 + n * 16 + row16;
    boff[n] = r * 64 + ((kgrp * 16) ^ xorpat(r));
  }

#define STAGE(t)                                                        \
  {                                                                     \
    const int b_ = (t) & 3;                                             \
    const size_t ko_ = (size_t)(t) * 64;                                \
    gload_lds16(gA0 + ko_, dA0 + b_ * bufA);                            \
    gload_lds16(gA1 + ko_, dA1 + b_ * bufA);                            \
    gload_lds16(gB0 + ko_, dB0 + b_ * bufB);                            \
  }

  f32x4 acc[4][4] = {};
  const int NT = K >> 5;
  STAGE(0);
  STAGE(1);

  for (int t = 0; t < NT; ++t) {
    const int b = t & 3;
    if (t + 2 < NT) {
      STAGE(t + 2);
      asm volatile("s_waitcnt vmcnt(6)" ::: "memory");   // tile t landed (6 newer in flight)
    } else if (t + 1 < NT) {
      asm volatile("s_waitcnt vmcnt(3)" ::: "memory");
    } else {
      asm volatile("s_waitcnt vmcnt(0)" ::: "memory");
    }
    __builtin_amdgcn_s_barrier();
    __builtin_amdgcn_sched_barrier(0);

    const char* La = (const char*)sA[b];
    const char* Lb = (const char*)sB[b];
    bf16x8 af0 = *(const bf16x8*)(La + aoff[0]);
    bf16x8 af1 = *(const bf16x8*)(La + aoff[1]);
    bf16x8 bf0 = *(const bf16x8*)(Lb + boff[0]);
    bf16x8 bf1 = *(const bf16x8*)(Lb + boff[1]);
    bf16x8 bf2 = *(const bf16x8*)(Lb + boff[2]);
    bf16x8 bf3 = *(const bf16x8*)(Lb + boff[3]);
    bf16x8 af2 = *(const bf16x8*)(La + aoff[2]);
    bf16x8 af3 = *(const bf16x8*)(La + aoff[3]);
    asm volatile("s_waitcnt lgkmcnt(2)" ::: "memory");
    __builtin_amdgcn_sched_barrier(0);
    __builtin_amdgcn_s_setprio(1);
    acc[0][0] = MFMA_BF16(af0, bf0, acc[0][0]);
    acc[0][1] = MFMA_BF16(af0, bf1, acc[0][1]);
    acc[0][2] = MFMA_BF16(af0, bf2, acc[0][2]);
    acc[0][3] = MFMA_BF16(af0, bf3, acc[0][3]);
    acc[1][0] = MFMA_BF16(af1, bf0, acc[1][0]);
    acc[1][1] = MFMA_BF16(af1, bf1, acc[1][1]);
    acc[1][2] = MFMA_BF16(af1, bf2, acc[1][2]);
    acc[1][3] = MFMA_BF16(af1, bf3, acc[1][3]);
    __builtin_amdgcn_s_setprio(0);
    asm volatile("s_waitcnt lgkmcnt(0)" ::: "memory");
    __builtin_amdgcn_sched_barrier(0);
    __builtin_amdgcn_s_setprio(1);
    acc[2][0] = MFMA_BF16(af2, bf0, acc[2][0]);
    acc[2][1] = MFMA_BF16(af2, bf1, acc[2][1]);
    acc[2][2] = MFMA_BF16(af2, bf2, acc[2][2]);
    acc[2][3] = MFMA_BF16(af2, bf3, acc[2][3]);
    acc[3][0] = MFMA_BF16(af3, bf0, acc[3][0]);
    acc[3][1] = MFMA_BF16(af3, bf1, acc[3][1]);
    acc[3][2] = MFMA_BF16(af3, bf2, acc[3][2]);
    acc[3][3] = MFMA_BF16(af3, bf3, acc[3][3]);
    __builtin_amdgcn_s_setprio(0);
  }
#undef STAGE

  // --- epilogue: C row = m0+wm*64+m*16+kgrp*4+r, col = n0+wn*64+n*16+row16 ---
#pragma unroll
  for (int m = 0; m < 4; m++) {
    const int rowb = m0 + wm * 64 + m * 16 + kgrp * 4;
#pragma unroll
    for (int n = 0; n < 4; n++) {
      const int col = n0 + wn * 64 + n * 16 + row16;
#pragma unroll
      for (int r = 0; r < 4; r++) {
        const float v = acc[m][n][r];
        const int rr2 = rowb + r;
        if constexpr (EPI == 0) {
          const int bb = rr2 >> 10, s = rr2 & 1023;
          if (col < 1024) {
            const int hh = col >> 6, d = col & 63;
            qb[(((size_t)(bb * NH_ + hh)) * S_ + s) * HD_ + d] = (bf16_t)(v * 0.125f);
          } else if (col < 2048) {
            const int c = col - 1024, hh = c >> 6, d = c & 63;
            kb[(((size_t)(bb * NH_ + hh)) * S_ + s) * HD_ + d] = (bf16_t)v;
          } else {
            const int c = col - 2048, hh = c >> 6, d = c & 63;
            vtb[(((size_t)(bb * NH_ + hh)) * HD_ + d) * S_ + s] = (bf16_t)v;
          }
        } else if constexpr (EPI == 2) {
          bout[(size_t)rr2 * N + col] = (bf16_t)fmaxf(v + bias[col], 0.0f);
        } else {
          fout[(size_t)rr2 * N + col] = v + bias[col];
        }
      }
    }
  }
}

// ---------------------------------------------------------------------------
// m97-structure GEMM (kept for N=1024 shapes: O-proj EPI=1, FFN2 EPI=3)
// ---------------------------------------------------------------------------
template <int EPI>
__global__ __launch_bounds__(256) void gemm_bt(
    const bf16_t* __restrict__ A, const bf16_t* __restrict__ W, int M, int N, int K,
    float* __restrict__ fout, const float* __restrict__ bias) {
  __shared__ bf16_t sA[128 * 32];
  __shared__ bf16_t sB[128 * 32];
  const int tid = threadIdx.x;
  const int wave = tid >> 6, lane = tid & 63;
  const int row16 = lane & 15, kgrp = lane >> 4;
  const int m0 = blockIdx.y * 128, n0 = blockIdx.x * 128;
  const int wr = wave >> 1, wc = wave & 1;

  const int srow  = lane >> 2;
  const int skoff = (lane & 3) * 8;
  const bf16_t* gA = A + (size_t)(m0 + wave * 32 + srow) * K + skoff;
  const bf16_t* gB = W + (size_t)(n0 + wave * 32 + srow) * K + skoff;
  bf16_t* lA0 = &sA[(wave * 2 + 0) * 512];
  bf16_t* lA1 = &sA[(wave * 2 + 1) * 512];
  bf16_t* lB0 = &sB[(wave * 2 + 0) * 512];
  bf16_t* lB1 = &sB[(wave * 2 + 1) * 512];

  f32x4 acc[4][4] = {};

  for (int k0 = 0; k0 < K; k0 += 32) {
    gload_lds16(gA + k0, lA0);
    gload_lds16(gA + k0 + (size_t)16 * K, lA1);
    gload_lds16(gB + k0, lB0);
    gload_lds16(gB + k0 + (size_t)16 * K, lB1);
    __syncthreads();
    bf16x8 af[4], bfr[4];
#pragma unroll
    for (int m = 0; m < 4; m++)
      af[m] = *(const bf16x8*)&sA[(wr * 64 + m * 16 + row16) * 32 + kgrp * 8];
#pragma unroll
    for (int n = 0; n < 4; n++)
      bfr[n] = *(const bf16x8*)&sB[(wc * 64 + n * 16 + row16) * 32 + kgrp * 8];
#pragma unroll
    for (int m = 0; m < 4; m++)
#pragma unroll
      for (int n = 0; n < 4; n++)
        acc[m][n] = MFMA_BF16(af[m], bfr[n], acc[m][n]);
    __syncthreads();
  }

#pragma unroll
  for (int m = 0; m < 4; m++) {
    const int rowb = m0 + wr * 64 + m * 16 + kgrp * 4;
#pragma unroll
    for (int n = 0; n < 4; n++) {
      const int col = n0 + wc * 64 + n * 16 + row16;
#pragma unroll
      for (int r = 0; r < 4; r++) {
        const float v = acc[m][n][r];
        const int rr = rowb + r;
        if constexpr (EPI == 1) {
          fout[(size_t)rr * N + col] += v;
        } else {
          fout[(size_t)rr * N + col] += v + bias[col];
        }
      }
    }
  }
}

// ---------------------------------------------------------------------------
// Flash attention (causal), unchanged from round 1
// ---------------------------------------------------------------------------
__global__ __launch_bounds__(256) void attn_flash(const bf16_t* __restrict__ qg,
                                                  const bf16_t* __restrict__ kg,
                                                  const bf16_t* __restrict__ vtg,
                                                  bf16_t* __restrict__ aout) {
  const int qtile = blockIdx.x;
  const int bh    = blockIdx.y;
  const int tid = threadIdx.x;
  const int wave = tid >> 6, lane = tid & 63;
  const int row16 = lane & 15, kgrp = lane >> 4;
  const int q0 = qtile * 64 + wave * 16;

  const bf16_t* qb = qg + (size_t)bh * S_ * HD_;
  const bf16_t* kb = kg + (size_t)bh * S_ * HD_;
  const bf16_t* vb = vtg + (size_t)bh * HD_ * S_;

  const bf16x8 qf0 = *(const bf16x8*)&qb[(size_t)(q0 + row16) * HD_ + kgrp * 8];
  const bf16x8 qf1 = *(const bf16x8*)&qb[(size_t)(q0 + row16) * HD_ + 32 + kgrp * 8];

  f32x4 accO[4] = {};
  float mrun[4] = {-1e30f, -1e30f, -1e30f, -1e30f};
  float lrun[4] = {0.f, 0.f, 0.f, 0.f};

  __shared__ bf16_t sP[4][16][32];

  const int kv_end = qtile * 64 + 64;
  for (int k0 = 0; k0 < kv_end; k0 += 32) {
    f32x4 sc0 = {}, sc1 = {};
    {
      bf16x8 kf0 = *(const bf16x8*)&kb[(size_t)(k0 + row16) * HD_ + kgrp * 8];
      bf16x8 kf1 = *(const bf16x8*)&kb[(size_t)(k0 + row16) * HD_ + 32 + kgrp * 8];
      sc0 = MFMA_BF16(qf0, kf0, sc0);
      sc0 = MFMA_BF16(qf1, kf1, sc0);
      bf16x8 kf2 = *(const bf16x8*)&kb[(size_t)(k0 + 16 + row16) * HD_ + kgrp * 8];
      bf16x8 kf3 = *(const bf16x8*)&kb[(size_t)(k0 + 16 + row16) * HD_ + 32 + kgrp * 8];
      sc1 = MFMA_BF16(qf0, kf2, sc1);
      sc1 = MFMA_BF16(qf1, kf3, sc1);
    }
    float p0[4], p1[4];
#pragma unroll
    for (int r = 0; r < 4; r++) {
      const int qglob = q0 + kgrp * 4 + r;
      float s0 = (k0 + row16 <= qglob) ? sc0[r] : -1e30f;
      float s1 = (k0 + 16 + row16 <= qglob) ? sc1[r] : -1e30f;
      float t = fmaxf(s0, s1);
#pragma unroll
      for (int msk = 1; msk < 16; msk <<= 1) t = fmaxf(t, __shfl_xor(t, msk, 64));
      const float mnew  = fmaxf(mrun[r], t);
      const float alpha = __expf(mrun[r] - mnew);
      const float e0 = __expf(s0 - mnew);
      const float e1 = __expf(s1 - mnew);
      float ls = e0 + e1;
#pragma unroll
      for (int msk = 1; msk < 16; msk <<= 1) ls += __shfl_xor(ls, msk, 64);
      lrun[r] = lrun[r] * alpha + ls;
      mrun[r] = mnew;
#pragma unroll
      for (int d = 0; d < 4; d++) accO[d][r] *= alpha;
      p0[r] = e0; p1[r] = e1;
    }
    __syncthreads();
#pragma unroll
    for (int r = 0; r < 4; r++) {
      sP[wave][kgrp * 4 + r][row16]      = (bf16_t)p0[r];
      sP[wave][kgrp * 4 + r][16 + row16] = (bf16_t)p1[r];
    }
    __syncthreads();
    const bf16x8 pf = *(const bf16x8*)&sP[wave][row16][kgrp * 8];
#pragma unroll
    for (int d = 0; d < 4; d++) {
      bf16x8 vf = *(const bf16x8*)&vb[(size_t)(d * 16 + row16) * S_ + k0 + kgrp * 8];
      accO[d] = MFMA_BF16(pf, vf, accO[d]);
    }
  }

  const int b = bh >> 4, hh = bh & 15;
#pragma unroll
  for (int d = 0; d < 4; d++)
#pragma unroll
    for (int r = 0; r < 4; r++) {
      const int tok = b * S_ + q0 + kgrp * 4 + r;
      aout[(size_t)tok * D_ + hh * HD_ + d * 16 + row16] = (bf16_t)(accO[d][r] / lrun[r]);
    }
}

// ---------------------------------------------------------------------------
// Launch
// ---------------------------------------------------------------------------
extern "C" void kernel_launch(void* const* d_in, const int* in_sizes, int n_in,
                              void* d_out, int out_size, void* d_ws, size_t ws_size,
                              hipStream_t stream) {
  const int*   x      = (const int*)d_in[0];
  const float* emb_W  = (const float*)d_in[1];
  const float* q_W    = (const float*)d_in[2];
  const float* k_W    = (const float*)d_in[3];
  const float* v_W    = (const float*)d_in[4];
  const float* o_W    = (const float*)d_in[5];
  const float* ln0_g  = (const float*)d_in[6];
  const float* ln0_b  = (const float*)d_in[7];
  const float* ln1_g  = (const float*)d_in[8];
  const float* ln1_b  = (const float*)d_in[9];
  const float* ffn_W1 = (const float*)d_in[10];
  const float* ffn_b1 = (const float*)d_in[11];
  const float* ffn_W2 = (const float*)d_in[12];
  const float* ffn_b2 = (const float*)d_in[13];
  const float* out_W  = (const float*)d_in[14];
  const float* out_b  = (const float*)d_in[15];
  float* out = (float*)d_out;

  char* p = (char*)d_ws;
  auto take = [&](size_t n) { char* r = p; p += (n + 255) & ~(size_t)255; return r; };
  float*  pe    = (float*)take((size_t)S_ * D_ * 4);
  float*  h     = (float*)take((size_t)TOK_ * D_ * 4);
  bf16_t* ain   = (bf16_t*)take((size_t)TOK_ * D_ * 2);
  bf16_t* attno = (bf16_t*)take((size_t)TOK_ * D_ * 2);
  bf16_t* qb    = (bf16_t*)take((size_t)B_ * NH_ * S_ * HD_ * 2);
  bf16_t* kb    = (bf16_t*)take((size_t)B_ * NH_ * S_ * HD_ * 2);
  bf16_t* vtb   = (bf16_t*)take((size_t)B_ * NH_ * S_ * HD_ * 2);
  bf16_t* ff    = (bf16_t*)take((size_t)TOK_ * HF_ * 2);
  bf16_t* qkvW  = (bf16_t*)take((size_t)3 * D_ * D_ * 2);
  bf16_t* oWb   = (bf16_t*)take((size_t)D_ * D_ * 2);
  bf16_t* W1b   = (bf16_t*)take((size_t)HF_ * D_ * 2);
  bf16_t* W2b   = (bf16_t*)take((size_t)D_ * HF_ * 2);
  bf16_t* outWb = (bf16_t*)take((size_t)V_ * D_ * 2);

  // --- weights -> bf16 ---
  cvt_f32_bf16<<<1024, 256, 0, stream>>>(q_W, qkvW, D_ * D_ / 4);
  cvt_f32_bf16<<<1024, 256, 0, stream>>>(k_W, qkvW + (size_t)D_ * D_, D_ * D_ / 4);
  cvt_f32_bf16<<<1024, 256, 0, stream>>>(v_W, qkvW + (size_t)2 * D_ * D_, D_ * D_ / 4);
  cvt_f32_bf16<<<1024, 256, 0, stream>>>(o_W, oWb, D_ * D_ / 4);
  cvt_f32_bf16<<<4096, 256, 0, stream>>>(ffn_W1, W1b, HF_ * D_ / 4);
  cvt_f32_bf16<<<4096, 256, 0, stream>>>(ffn_W2, W2b, D_ * HF_ / 4);
  cvt_f32_bf16<<<32000, 256, 0, stream>>>(out_W, outWb, V_ * D_ / 4);

  // --- embedding + PE ---
  pe_kernel<<<S_, 256, 0, stream>>>(pe);
  embed_kernel<<<TOK_ * D_ / 4 / 256, 256, 0, stream>>>(x, emb_W, pe, h);

  // --- transformer blocks (shared weights) ---
  for (int blk = 0; blk < 4; blk++) {
    ln_res_kernel<<<TOK_, 256, 0, stream>>>(h, ln0_g, ln0_b, ain);
    gemm_pipe<0><<<16 * (3 * D_ / 128), 512, 0, stream>>>(
        ain, qkvW, 3 * D_, D_, nullptr, nullptr, nullptr, qb, kb, vtb);
    attn_flash<<<dim3(S_ / 64, B_ * NH_), 256, 0, stream>>>(qb, kb, vtb, attno);
    gemm_bt<1><<<dim3(D_ / 128, TOK_ / 128), 256, 0, stream>>>(
        attno, oWb, TOK_, D_, D_, h, nullptr);
    ln_res_kernel<<<TOK_, 256, 0, stream>>>(h, ln1_g, ln1_b, ain);
    gemm_pipe<2><<<16 * (HF_ / 128), 512, 0, stream>>>(
        ain, W1b, HF_, D_, nullptr, ffn_b1, ff, nullptr, nullptr, nullptr);
    gemm_bt<3><<<dim3(D_ / 128, TOK_ / 128), 256, 0, stream>>>(
        ff, W2b, TOK_, D_, HF_, h, ffn_b2);
  }

  // --- final logits ---
  cvt_f32_bf16<<<4096, 256, 0, stream>>>(h, ain, TOK_ * D_ / 4);
  gemm_pipe<4><<<16 * (V_ / 128), 512, 0, stream>>>(
      ain, outWb, V_, D_, out, out_b, nullptr, nullptr, nullptr, nullptr);
}

// Round 3
// 1911.294 us; speedup vs baseline: 1.1463x; 1.1463x over previous
//
#include <hip/hip_runtime.h>
#include <hip/hip_bf16.h>
#include <math.h>

// ---------------------------------------------------------------------------
// Types
// ---------------------------------------------------------------------------
typedef __bf16 bf16_t;
typedef __bf16 bf16x8 __attribute__((ext_vector_type(8)));
typedef __bf16 bf16x4 __attribute__((ext_vector_type(4)));
typedef float  f32x4  __attribute__((ext_vector_type(4)));

#define MFMA_BF16(a, b, c) __builtin_amdgcn_mfma_f32_16x16x32_bf16((a), (b), (c), 0, 0, 0)

typedef const void __attribute__((address_space(1)))* gas_ptr;
typedef void       __attribute__((address_space(3)))* las_ptr;

__device__ __forceinline__ void gload_lds16(const void* g, void* l) {
  // global -> LDS direct, 16B per lane. LDS dest is wave-uniform base + lane*16.
  __builtin_amdgcn_global_load_lds((gas_ptr)g, (las_ptr)l, 16, 0, 0);
}

// ---------------------------------------------------------------------------
// Model constants
// ---------------------------------------------------------------------------
static constexpr int B_ = 4, S_ = 1024, D_ = 1024, HF_ = 4096, V_ = 32000;
static constexpr int NH_ = 16, HD_ = 64;
static constexpr int TOK_ = B_ * S_;  // 4096

// ---------------------------------------------------------------------------
// fp32 -> bf16 conversion (vectorized x4)
// ---------------------------------------------------------------------------
__global__ __launch_bounds__(256) void cvt_f32_bf16(const float* __restrict__ in,
                                                    bf16_t* __restrict__ out, int n4) {
  int i = blockIdx.x * 256 + threadIdx.x;
  if (i < n4) {
    float4 v = ((const float4*)in)[i];
    bf16x4 o;
    o[0] = (bf16_t)v.x; o[1] = (bf16_t)v.y; o[2] = (bf16_t)v.z; o[3] = (bf16_t)v.w;
    ((bf16x4*)out)[i] = o;
  }
}

// ---------------------------------------------------------------------------
// Sinusoidal positional encoding table
// ---------------------------------------------------------------------------
__global__ __launch_bounds__(256) void pe_kernel(float* __restrict__ pe) {
  const int s = blockIdx.x;
  for (int i = threadIdx.x; i < D_ / 2; i += 256) {
    float div = expf((2.0f * (float)i) * (-9.210340371976184f / (float)D_)); // ln(10000)
    float a = (float)s * div;
    pe[(size_t)s * D_ + 2 * i]     = sinf(a);
    pe[(size_t)s * D_ + 2 * i + 1] = cosf(a);
  }
}

// ---------------------------------------------------------------------------
// Embedding: h[t][d] = emb_W[x[t]][d] * 32 + pe[t % S][d]
// ---------------------------------------------------------------------------
__global__ __launch_bounds__(256) void embed_kernel(const int* __restrict__ x,
                                                    const float* __restrict__ embW,
                                                    const float* __restrict__ pe,
                                                    float* __restrict__ h) {
  int i = blockIdx.x * 256 + threadIdx.x;
  int token = i >> 8;
  int c4 = i & 255;
  int idx = x[token];
  float4 e = ((const float4*)(embW + (size_t)idx * D_))[c4];
  float4 p = ((const float4*)(pe + (size_t)(token & (S_ - 1)) * D_))[c4];
  float4 o;
  o.x = e.x * 32.0f + p.x; o.y = e.y * 32.0f + p.y;
  o.z = e.z * 32.0f + p.z; o.w = e.w * 32.0f + p.w;
  ((float4*)(h + (size_t)token * D_))[c4] = o;
}

// ---------------------------------------------------------------------------
// a_in = h + LayerNorm(h)*g + b   -> bf16
// ---------------------------------------------------------------------------
__global__ __launch_bounds__(256) void ln_res_kernel(const float* __restrict__ h,
                                                     const float* __restrict__ gamma,
                                                     const float* __restrict__ beta,
                                                     bf16_t* __restrict__ out) {
  const int row = blockIdx.x;
  const int tid = threadIdx.x;
  const float4 v = ((const float4*)(h + (size_t)row * D_))[tid];
  float s  = v.x + v.y + v.z + v.w;
  float s2 = v.x * v.x + v.y * v.y + v.z * v.z + v.w * v.w;
#pragma unroll
  for (int m = 1; m < 64; m <<= 1) {
    s  += __shfl_xor(s, m, 64);
    s2 += __shfl_xor(s2, m, 64);
  }
  __shared__ float red[2][4];
  const int wave = tid >> 6, lane = tid & 63;
  if (lane == 0) { red[0][wave] = s; red[1][wave] = s2; }
  __syncthreads();
  s  = red[0][0] + red[0][1] + red[0][2] + red[0][3];
  s2 = red[1][0] + red[1][1] + red[1][2] + red[1][3];
  const float mu   = s * (1.0f / D_);
  const float rstd = rsqrtf(s2 * (1.0f / D_) - mu * mu + 1e-5f);
  const float4 g4 = ((const float4*)gamma)[tid];
  const float4 b4 = ((const float4*)beta)[tid];
  bf16x4 o;
  o[0] = (bf16_t)(v.x + (v.x - mu) * rstd * g4.x + b4.x);
  o[1] = (bf16_t)(v.y + (v.y - mu) * rstd * g4.y + b4.y);
  o[2] = (bf16_t)(v.z + (v.z - mu) * rstd * g4.z + b4.z);
  o[3] = (bf16_t)(v.w + (v.w - mu) * rstd * g4.w + b4.w);
  ((bf16x4*)(out + (size_t)row * D_))[tid] = o;
}

// ---------------------------------------------------------------------------
// Deep-pipelined GEMM: C[4096,N] = A[4096,K] @ W[N,K]^T   (K multiple of 32)
// Tile 256x256, 8 waves (2M x 4N), BK=32, 4 rotating LDS buffers (128 KB),
// 3-tile prefetch depth, counted vmcnt(8)/lgkmcnt(4,0), 1 barrier/tile,
// setprio around MFMA clusters, bank swizzle ((r>>1)&3)<<4 applied as an
// involution (pre-swizzled global source + swizzled ds_read, linear LDS dest),
// M-fastest block order + XCD swizzle (grid multiple of 8).
// Epilogues: 0 QKV-scatter, 2 bias+relu->bf16, 4 bias->f32.
// ---------------------------------------------------------------------------
template <int EPI>
__global__ __launch_bounds__(512, 2) void gemm_pipe(
    const bf16_t* __restrict__ A, const bf16_t* __restrict__ W, int N, int K,
    float* __restrict__ fout, const float* __restrict__ bias, bf16_t* __restrict__ bout,
    bf16_t* __restrict__ qb, bf16_t* __restrict__ kb, bf16_t* __restrict__ vtb) {
  __shared__ bf16_t sA[4][256 * 32];  // 64 KB: 4 bufs, 256 rows x 64 B
  __shared__ bf16_t sB[4][256 * 32];  // 64 KB

  const int tid = threadIdx.x;
  const int wave = tid >> 6, lane = tid & 63;
  const int row16 = lane & 15, kgrp = lane >> 4;
  const int wm = wave >> 2, wn = wave & 3;  // 2 x 4 wave grid

  // block swizzle: XCD-bijective (grid % 8 == 0), then M-fastest (16 M-tiles)
  const int nb = gridDim.x;
  const int logical = (blockIdx.x & 7) * (nb >> 3) + (blockIdx.x >> 3);
  const int m0 = (logical & 15) << 8;
  const int n0 = (logical >> 4) << 8;

  // staging: thread covers row sr, 16 B at swizzled byte col within 64B row
  const int sr = wave * 16 + (lane >> 2);          // 0..127
  const int sw = ((lane & 3) * 16) ^ (((sr >> 1) & 3) << 4);
  const char* gA0 = (const char*)(A + (size_t)(m0 + sr) * K) + sw;
  const char* gA1 = (const char*)(A + (size_t)(m0 + sr + 128) * K) + sw;
  const char* gB0 = (const char*)(W + (size_t)(n0 + sr) * K) + sw;
  const char* gB1 = (const char*)(W + (size_t)(n0 + sr + 128) * K) + sw;
  char* const dA = (char*)&sA[0][0] + wave * 1024;  // + lane*16 by HW
  char* const dB = (char*)&sB[0][0] + wave * 1024;

  // swizzled ds_read byte offsets (same involution)
  int aoff[8], boff[4];
#pragma unroll
  for (int m = 0; m < 8; m++) {
    const int r = wm * 128 + m * 16 + row16;
    aoff[m] = r * 64 + ((kgrp * 16) ^ (((r >> 1) & 3) << 4));
  }
#pragma unroll
  for (int n = 0; n < 4; n++) {
    const int r = wn * 64 + n * 16 + row16;
    boff[n] = r * 64 + ((kgrp * 16) ^ (((r >> 1) & 3) << 4));
  }

#define STAGE(t)                                          \
  {                                                       \
    const int b_ = (t) & 3;                               \
    const size_t ko_ = (size_t)(t) * 64;                  \
    gload_lds16(gA0 + ko_, dA + b_ * 16384);              \
    gload_lds16(gA1 + ko_, dA + b_ * 16384 + 8192);       \
    gload_lds16(gB0 + ko_, dB + b_ * 16384);              \
    gload_lds16(gB1 + ko_, dB + b_ * 16384 + 8192);       \
  }

  f32x4 acc[8][4] = {};
  const int NT = K >> 5;  // >= 4 for all our shapes

  STAGE(0); STAGE(1); STAGE(2);
  asm volatile("s_waitcnt vmcnt(8)" ::: "memory");  // tile 0 landed

  for (int t = 0; t < NT; ++t) {
    __builtin_amdgcn_s_barrier();  // tile t visible to all; prev reads done
    const char* La = (const char*)&sA[t & 3][0];
    const char* Lb = (const char*)&sB[t & 3][0];
    bf16x8 a0 = *(const bf16x8*)(La + aoff[0]);
    bf16x8 a1 = *(const bf16x8*)(La + aoff[1]);
    bf16x8 a2 = *(const bf16x8*)(La + aoff[2]);
    bf16x8 a3 = *(const bf16x8*)(La + aoff[3]);
    bf16x8 b0 = *(const bf16x8*)(Lb + boff[0]);
    bf16x8 b1 = *(const bf16x8*)(Lb + boff[1]);
    bf16x8 b2 = *(const bf16x8*)(Lb + boff[2]);
    bf16x8 b3 = *(const bf16x8*)(Lb + boff[3]);
    __builtin_amdgcn_sched_barrier(0);  // pin first-8 / last-4 ds_read split
    bf16x8 a4 = *(const bf16x8*)(La + aoff[4]);
    bf16x8 a5 = *(const bf16x8*)(La + aoff[5]);
    bf16x8 a6 = *(const bf16x8*)(La + aoff[6]);
    bf16x8 a7 = *(const bf16x8*)(La + aoff[7]);
    if (t + 3 < NT) STAGE(t + 3);
    asm volatile("s_waitcnt lgkmcnt(4)" ::: "memory");  // a0-3,b0-3 ready
    __builtin_amdgcn_sched_barrier(0);
    __builtin_amdgcn_s_setprio(1);
    acc[0][0] = MFMA_BF16(a0, b0, acc[0][0]);
    acc[0][1] = MFMA_BF16(a0, b1, acc[0][1]);
    acc[0][2] = MFMA_BF16(a0, b2, acc[0][2]);
    acc[0][3] = MFMA_BF16(a0, b3, acc[0][3]);
    acc[1][0] = MFMA_BF16(a1, b0, acc[1][0]);
    acc[1][1] = MFMA_BF16(a1, b1, acc[1][1]);
    acc[1][2] = MFMA_BF16(a1, b2, acc[1][2]);
    acc[1][3] = MFMA_BF16(a1, b3, acc[1][3]);
    acc[2][0] = MFMA_BF16(a2, b0, acc[2][0]);
    acc[2][1] = MFMA_BF16(a2, b1, acc[2][1]);
    acc[2][2] = MFMA_BF16(a2, b2, acc[2][2]);
    acc[2][3] = MFMA_BF16(a2, b3, acc[2][3]);
    acc[3][0] = MFMA_BF16(a3, b0, acc[3][0]);
    acc[3][1] = MFMA_BF16(a3, b1, acc[3][1]);
    acc[3][2] = MFMA_BF16(a3, b2, acc[3][2]);
    acc[3][3] = MFMA_BF16(a3, b3, acc[3][3]);
    __builtin_amdgcn_s_setprio(0);
    asm volatile("s_waitcnt lgkmcnt(0)" ::: "memory");  // a4-7 ready
    __builtin_amdgcn_sched_barrier(0);
    __builtin_amdgcn_s_setprio(1);
    acc[4][0] = MFMA_BF16(a4, b0, acc[4][0]);
    acc[4][1] = MFMA_BF16(a4, b1, acc[4][1]);
    acc[4][2] = MFMA_BF16(a4, b2, acc[4][2]);
    acc[4][3] = MFMA_BF16(a4, b3, acc[4][3]);
    acc[5][0] = MFMA_BF16(a5, b0, acc[5][0]);
    acc[5][1] = MFMA_BF16(a5, b1, acc[5][1]);
    acc[5][2] = MFMA_BF16(a5, b2, acc[5][2]);
    acc[5][3] = MFMA_BF16(a5, b3, acc[5][3]);
    acc[6][0] = MFMA_BF16(a6, b0, acc[6][0]);
    acc[6][1] = MFMA_BF16(a6, b1, acc[6][1]);
    acc[6][2] = MFMA_BF16(a6, b2, acc[6][2]);
    acc[6][3] = MFMA_BF16(a6, b3, acc[6][3]);
    acc[7][0] = MFMA_BF16(a7, b0, acc[7][0]);
    acc[7][1] = MFMA_BF16(a7, b1, acc[7][1]);
    acc[7][2] = MFMA_BF16(a7, b2, acc[7][2]);
    acc[7][3] = MFMA_BF16(a7, b3, acc[7][3]);
    __builtin_amdgcn_s_setprio(0);
    // wait: tile t+1's stage landed (per-wave; barrier makes it collective)
    if (t + 3 < NT) {
      asm volatile("s_waitcnt vmcnt(8)" ::: "memory");
    } else if (t + 2 < NT) {
      asm volatile("s_waitcnt vmcnt(4)" ::: "memory");
    } else if (t + 1 < NT) {
      asm volatile("s_waitcnt vmcnt(0)" ::: "memory");
    }
  }
#undef STAGE

  // epilogue: C row = m0+wm*128+m*16+kgrp*4+r, col = n0+wn*64+n*16+row16
#pragma unroll
  for (int m = 0; m < 8; m++) {
    const int rowb = m0 + wm * 128 + m * 16 + kgrp * 4;
#pragma unroll
    for (int n = 0; n < 4; n++) {
      const int col = n0 + wn * 64 + n * 16 + row16;
#pragma unroll
      for (int r = 0; r < 4; r++) {
        const float v = acc[m][n][r];
        const int rr2 = rowb + r;
        if constexpr (EPI == 0) {
          const int bb = rr2 >> 10, s = rr2 & 1023;
          if (col < 1024) {
            const int hh = col >> 6, d = col & 63;
            qb[(((size_t)(bb * NH_ + hh)) * S_ + s) * HD_ + d] = (bf16_t)(v * 0.125f);
          } else if (col < 2048) {
            const int c = col - 1024, hh = c >> 6, d = c & 63;
            kb[(((size_t)(bb * NH_ + hh)) * S_ + s) * HD_ + d] = (bf16_t)v;
          } else {
            const int c = col - 2048, hh = c >> 6, d = c & 63;
            vtb[(((size_t)(bb * NH_ + hh)) * HD_ + d) * S_ + s] = (bf16_t)v;
          }
        } else if constexpr (EPI == 2) {
          bout[(size_t)rr2 * N + col] = (bf16_t)fmaxf(v + bias[col], 0.0f);
        } else {
          fout[(size_t)rr2 * N + col] = v + bias[col];
        }
      }
    }
  }
}

// ---------------------------------------------------------------------------
// m97-structure GEMM (N=1024 shapes: O-proj EPI=1, FFN2 EPI=3)
// ---------------------------------------------------------------------------
template <int EPI>
__global__ __launch_bounds__(256) void gemm_bt(
    const bf16_t* __restrict__ A, const bf16_t* __restrict__ W, int M, int N, int K,
    float* __restrict__ fout, const float* __restrict__ bias) {
  __shared__ bf16_t sA[128 * 32];
  __shared__ bf16_t sB[128 * 32];
  const int tid = threadIdx.x;
  const int wave = tid >> 6, lane = tid & 63;
  const int row16 = lane & 15, kgrp = lane >> 4;
  const int m0 = blockIdx.y * 128, n0 = blockIdx.x * 128;
  const int wr = wave >> 1, wc = wave & 1;

  const int srow  = lane >> 2;
  const int skoff = (lane & 3) * 8;
  const bf16_t* gA = A + (size_t)(m0 + wave * 32 + srow) * K + skoff;
  const bf16_t* gB = W + (size_t)(n0 + wave * 32 + srow) * K + skoff;
  bf16_t* lA0 = &sA[(wave * 2 + 0) * 512];
  bf16_t* lA1 = &sA[(wave * 2 + 1) * 512];
  bf16_t* lB0 = &sB[(wave * 2 + 0) * 512];
  bf16_t* lB1 = &sB[(wave * 2 + 1) * 512];

  f32x4 acc[4][4] = {};

  for (int k0 = 0; k0 < K; k0 += 32) {
    gload_lds16(gA + k0, lA0);
    gload_lds16(gA + k0 + (size_t)16 * K, lA1);
    gload_lds16(gB + k0, lB0);
    gload_lds16(gB + k0 + (size_t)16 * K, lB1);
    __syncthreads();
    bf16x8 af[4], bfr[4];
#pragma unroll
    for (int m = 0; m < 4; m++)
      af[m] = *(const bf16x8*)&sA[(wr * 64 + m * 16 + row16) * 32 + kgrp * 8];
#pragma unroll
    for (int n = 0; n < 4; n++)
      bfr[n] = *(const bf16x8*)&sB[(wc * 64 + n * 16 + row16) * 32 + kgrp * 8];
#pragma unroll
    for (int m = 0; m < 4; m++)
#pragma unroll
      for (int n = 0; n < 4; n++)
        acc[m][n] = MFMA_BF16(af[m], bfr[n], acc[m][n]);
    __syncthreads();
  }

#pragma unroll
  for (int m = 0; m < 4; m++) {
    const int rowb = m0 + wr * 64 + m * 16 + kgrp * 4;
#pragma unroll
    for (int n = 0; n < 4; n++) {
      const int col = n0 + wc * 64 + n * 16 + row16;
#pragma unroll
      for (int r = 0; r < 4; r++) {
        const float v = acc[m][n][r];
        const int rr = rowb + r;
        if constexpr (EPI == 1) {
          fout[(size_t)rr * N + col] += v;
        } else {
          fout[(size_t)rr * N + col] += v + bias[col];
        }
      }
    }
  }
}

// ---------------------------------------------------------------------------
// Flash attention (causal), unchanged
// ---------------------------------------------------------------------------
__global__ __launch_bounds__(256) void attn_flash(const bf16_t* __restrict__ qg,
                                                  const bf16_t* __restrict__ kg,
                                                  const bf16_t* __restrict__ vtg,
                                                  bf16_t* __restrict__ aout) {
  const int qtile = blockIdx.x;
  const int bh    = blockIdx.y;
  const int tid = threadIdx.x;
  const int wave = tid >> 6, lane = tid & 63;
  const int row16 = lane & 15, kgrp = lane >> 4;
  const int q0 = qtile * 64 + wave * 16;

  const bf16_t* qb = qg + (size_t)bh * S_ * HD_;
  const bf16_t* kb = kg + (size_t)bh * S_ * HD_;
  const bf16_t* vb = vtg + (size_t)bh * HD_ * S_;

  const bf16x8 qf0 = *(const bf16x8*)&qb[(size_t)(q0 + row16) * HD_ + kgrp * 8];
  const bf16x8 qf1 = *(const bf16x8*)&qb[(size_t)(q0 + row16) * HD_ + 32 + kgrp * 8];

  f32x4 accO[4] = {};
  float mrun[4] = {-1e30f, -1e30f, -1e30f, -1e30f};
  float lrun[4] = {0.f, 0.f, 0.f, 0.f};

  __shared__ bf16_t sP[4][16][32];

  const int kv_end = qtile * 64 + 64;
  for (int k0 = 0; k0 < kv_end; k0 += 32) {
    f32x4 sc0 = {}, sc1 = {};
    {
      bf16x8 kf0 = *(const bf16x8*)&kb[(size_t)(k0 + row16) * HD_ + kgrp * 8];
      bf16x8 kf1 = *(const bf16x8*)&kb[(size_t)(k0 + row16) * HD_ + 32 + kgrp * 8];
      sc0 = MFMA_BF16(qf0, kf0, sc0);
      sc0 = MFMA_BF16(qf1, kf1, sc0);
      bf16x8 kf2 = *(const bf16x8*)&kb[(size_t)(k0 + 16 + row16) * HD_ + kgrp * 8];
      bf16x8 kf3 = *(const bf16x8*)&kb[(size_t)(k0 + 16 + row16) * HD_ + 32 + kgrp * 8];
      sc1 = MFMA_BF16(qf0, kf2, sc1);
      sc1 = MFMA_BF16(qf1, kf3, sc1);
    }
    float p0[4], p1[4];
#pragma unroll
    for (int r = 0; r < 4; r++) {
      const int qglob = q0 + kgrp * 4 + r;
      float s0 = (k0 + row16 <= qglob) ? sc0[r] : -1e30f;
      float s1 = (k0 + 16 + row16 <= qglob) ? sc1[r] : -1e30f;
      float t = fmaxf(s0, s1);
#pragma unroll
      for (int msk = 1; msk < 16; msk <<= 1) t = fmaxf(t, __shfl_xor(t, msk, 64));
      const float mnew  = fmaxf(mrun[r], t);
      const float alpha = __expf(mrun[r] - mnew);
      const float e0 = __expf(s0 - mnew);
      const float e1 = __expf(s1 - mnew);
      float ls = e0 + e1;
#pragma unroll
      for (int msk = 1; msk < 16; msk <<= 1) ls += __shfl_xor(ls, msk, 64);
      lrun[r] = lrun[r] * alpha + ls;
      mrun[r] = mnew;
#pragma unroll
      for (int d = 0; d < 4; d++) accO[d][r] *= alpha;
      p0[r] = e0; p1[r] = e1;
    }
    __syncthreads();
#pragma unroll
    for (int r = 0; r < 4; r++) {
      sP[wave][kgrp * 4 + r][row16]      = (bf16_t)p0[r];
      sP[wave][kgrp * 4 + r][16 + row16] = (bf16_t)p1[r];
    }
    __syncthreads();
    const bf16x8 pf = *(const bf16x8*)&sP[wave][row16][kgrp * 8];
#pragma unroll
    for (int d = 0; d < 4; d++) {
      bf16x8 vf = *(const bf16x8*)&vb[(size_t)(d * 16 + row16) * S_ + k0 + kgrp * 8];
      accO[d] = MFMA_BF16(pf, vf, accO[d]);
    }
  }

  const int b = bh >> 4, hh = bh & 15;
#pragma unroll
  for (int d = 0; d < 4; d++)
#pragma unroll
    for (int r = 0; r < 4; r++) {
      const int tok = b * S_ + q0 + kgrp * 4 + r;
      aout[(size_t)tok * D_ + hh * HD_ + d * 16 + row16] = (bf16_t)(accO[d][r] / lrun[r]);
    }
}

// ---------------------------------------------------------------------------
// Launch
// ---------------------------------------------------------------------------
extern "C" void kernel_launch(void* const* d_in, const int* in_sizes, int n_in,
                              void* d_out, int out_size, void* d_ws, size_t ws_size,
                              hipStream_t stream) {
  const int*   x      = (const int*)d_in[0];
  const float* emb_W  = (const float*)d_in[1];
  const float* q_W    = (const float*)d_in[2];
  const float* k_W    = (const float*)d_in[3];
  const float* v_W    = (const float*)d_in[4];
  const float* o_W    = (const float*)d_in[5];
  const float* ln0_g  = (const float*)d_in[6];
  const float* ln0_b  = (const float*)d_in[7];
  const float* ln1_g  = (const float*)d_in[8];
  const float* ln1_b  = (const float*)d_in[9];
  const float* ffn_W1 = (const float*)d_in[10];
  const float* ffn_b1 = (const float*)d_in[11];
  const float* ffn_W2 = (const float*)d_in[12];
  const float* ffn_b2 = (const float*)d_in[13];
  const float* out_W  = (const float*)d_in[14];
  const float* out_b  = (const float*)d_in[15];
  float* out = (float*)d_out;

  char* p = (char*)d_ws;
  auto take = [&](size_t n) { char* r = p; p += (n + 255) & ~(size_t)255; return r; };
  float*  pe    = (float*)take((size_t)S_ * D_ * 4);
  float*  h     = (float*)take((size_t)TOK_ * D_ * 4);
  bf16_t* ain   = (bf16_t*)take((size_t)TOK_ * D_ * 2);
  bf16_t* attno = (bf16_t*)take((size_t)TOK_ * D_ * 2);
  bf16_t* qb    = (bf16_t*)take((size_t)B_ * NH_ * S_ * HD_ * 2);
  bf16_t* kb    = (bf16_t*)take((size_t)B_ * NH_ * S_ * HD_ * 2);
  bf16_t* vtb   = (bf16_t*)take((size_t)B_ * NH_ * S_ * HD_ * 2);
  bf16_t* ff    = (bf16_t*)take((size_t)TOK_ * HF_ * 2);
  bf16_t* qkvW  = (bf16_t*)take((size_t)3 * D_ * D_ * 2);
  bf16_t* oWb   = (bf16_t*)take((size_t)D_ * D_ * 2);
  bf16_t* W1b   = (bf16_t*)take((size_t)HF_ * D_ * 2);
  bf16_t* W2b   = (bf16_t*)take((size_t)D_ * HF_ * 2);
  bf16_t* outWb = (bf16_t*)take((size_t)V_ * D_ * 2);

  // --- weights -> bf16 ---
  cvt_f32_bf16<<<1024, 256, 0, stream>>>(q_W, qkvW, D_ * D_ / 4);
  cvt_f32_bf16<<<1024, 256, 0, stream>>>(k_W, qkvW + (size_t)D_ * D_, D_ * D_ / 4);
  cvt_f32_bf16<<<1024, 256, 0, stream>>>(v_W, qkvW + (size_t)2 * D_ * D_, D_ * D_ / 4);
  cvt_f32_bf16<<<1024, 256, 0, stream>>>(o_W, oWb, D_ * D_ / 4);
  cvt_f32_bf16<<<4096, 256, 0, stream>>>(ffn_W1, W1b, HF_ * D_ / 4);
  cvt_f32_bf16<<<4096, 256, 0, stream>>>(ffn_W2, W2b, D_ * HF_ / 4);
  cvt_f32_bf16<<<32000, 256, 0, stream>>>(out_W, outWb, V_ * D_ / 4);

  // --- embedding + PE ---
  pe_kernel<<<S_, 256, 0, stream>>>(pe);
  embed_kernel<<<TOK_ * D_ / 4 / 256, 256, 0, stream>>>(x, emb_W, pe, h);

  // --- transformer blocks (shared weights) ---
  for (int blk = 0; blk < 4; blk++) {
    ln_res_kernel<<<TOK_, 256, 0, stream>>>(h, ln0_g, ln0_b, ain);
    gemm_pipe<0><<<16 * (3 * D_ / 256), 512, 0, stream>>>(
        ain, qkvW, 3 * D_, D_, nullptr, nullptr, nullptr, qb, kb, vtb);
    attn_flash<<<dim3(S_ / 64, B_ * NH_), 256, 0, stream>>>(qb, kb, vtb, attno);
    gemm_bt<1><<<dim3(D_ / 128, TOK_ / 128), 256, 0, stream>>>(
        attno, oWb, TOK_, D_, D_, h, nullptr);
    ln_res_kernel<<<TOK_, 256, 0, stream>>>(h, ln1_g, ln1_b, ain);
    gemm_pipe<2><<<16 * (HF_ / 256), 512, 0, stream>>>(
        ain, W1b, HF_, D_, nullptr, ffn_b1, ff, nullptr, nullptr, nullptr);
    gemm_bt<3><<<dim3(D_ / 128, TOK_ / 128), 256, 0, stream>>>(
        ff, W2b, TOK_, D_, HF_, h, ffn_b2);
  }

  // --- final logits ---
  cvt_f32_bf16<<<4096, 256, 0, stream>>>(h, ain, TOK_ * D_ / 4);
  gemm_pipe<4><<<16 * (V_ / 256), 512, 0, stream>>>(
      ain, outWb, V_, D_, out, out_b, nullptr, nullptr, nullptr, nullptr);
}